// Round 1
// baseline (575.919 us; speedup 1.0000x reference)
//
#include <hip/hip_runtime.h>

typedef unsigned short u16;
typedef unsigned int u32;
typedef __bf16 bfx8 __attribute__((ext_vector_type(8)));
typedef float f32x4 __attribute__((ext_vector_type(4)));

#define Tn 8192
#define Bn 4
#define MTOT 32768

// ---- ws layout (bytes) ----
#define OFF_W     0ul
#define OFF_AL2   917504ul
#define OFF_XN    (1ul<<20)    // 16 MiB (reused as ytmp)
#define OFF_XIN   (17ul<<20)   // 32 MiB (reused as ygated)
#define OFF_Z     (49ul<<20)   // 32 MiB
#define OFF_U     (81ul<<20)   // 32 MiB
#define OFF_DBL   (113ul<<20)  // 4 MiB
#define OFF_DELTA (117ul<<20)  // 32 MiB
#define OFF_P     (149ul<<20)  // 16 MiB (becomes h0 after pass B)
#define OFF_CC    (165ul<<20)  // 16 MiB ; total 181 MiB

__device__ __forceinline__ float b2f(u16 h){ return __uint_as_float(((u32)h)<<16); }
__device__ __forceinline__ u16 f2b(float f){
  u32 u = __float_as_uint(f);
  return (u16)((u + 0x7FFFu + ((u>>16)&1u)) >> 16);
}

// ---------------- weight convert / pad / A-table ----------------
__global__ void wconv_k(const float* __restrict__ inw, const float* __restrict__ xpw,
                        const float* __restrict__ dtw, const float* __restrict__ opw,
                        const float* __restrict__ alog, u16* __restrict__ W, float* __restrict__ aL2)
{
  int i = blockIdx.x*256 + threadIdx.x;
  if (i < 262144) { W[i] = f2b(inw[i]); return; }                       // in_proj (1024x256)
  if (i < 294912) { int j = i - 262144; int r = j >> 9, k = j & 511;    // x_proj padded (64x512)
    float v = (r < 16) ? xpw[r*512 + k] : ((r < 32) ? 0.f : xpw[(r-16)*512 + k]);
    W[i] = f2b(v); return; }
  if (i < 311296) { int j = i - 294912; int d = j >> 5, k = j & 31;     // dt_proj padded (512x32)
    W[i] = f2b((k < 16) ? dtw[d*16 + k] : 0.f); return; }
  if (i < 442368) { W[i] = f2b(opw[i - 311296]); return; }              // out_proj (256x512)
  if (i < 450560) { int j = i - 442368; aL2[j] = -__expf(alog[j]) * 1.44269504088896f; return; }
}

// ---------------- LayerNorm over C, write xn (B,T,C) bf16 ----------------
__global__ __launch_bounds__(256)
void ln_k(const float* __restrict__ x, const float* __restrict__ lnw,
          const float* __restrict__ lnb, u16* __restrict__ xn)
{
  const int t0 = blockIdx.x*64, b = blockIdx.y;
  const int tid = threadIdx.x, cg = tid>>6, tl = tid&63;
  __shared__ float ps[4][64], pq[4][64], mu[64], rs[64];
  float s = 0.f, q = 0.f;
  for (int ci = 0; ci < 64; ci++){
    int c = ci*4 + cg;
    float v = x[((size_t)(b*256 + c))*Tn + t0 + tl];
    s += v; q += v*v;
  }
  ps[cg][tl] = s; pq[cg][tl] = q;
  __syncthreads();
  if (tid < 64){
    float S = ps[0][tid]+ps[1][tid]+ps[2][tid]+ps[3][tid];
    float Q = pq[0][tid]+pq[1][tid]+pq[2][tid]+pq[3][tid];
    float m = S*(1.f/256.f);
    float var = Q*(1.f/256.f) - m*m;
    mu[tid] = m; rs[tid] = rsqrtf(var + 1e-5f);
  }
  __syncthreads();
  const float w = lnw[tid&255], bb = lnb[tid&255];
  for (int t = 0; t < 64; t++){
    float v = x[((size_t)(b*256 + tid))*Tn + t0 + t];
    xn[((size_t)(b*Tn) + t0 + t)*256 + tid] = f2b((v - mu[t])*rs[t]*w + bb);
  }
}

// ---------------- generic bf16 MFMA GEMM: out[m][n] = sum_k A[m][k]*Bw[n][k] ----------------
// EPI 0: store bf16 ; EPI 1: softplus(v+bias[n]) bf16 ; EPI 2: split col<512 -> O, else O2
template<int BN, int EPI>
__global__ __launch_bounds__(256)
void gemm_k(const u16* __restrict__ A, int lda,
            const u16* __restrict__ Bw, int ldb,
            u16* __restrict__ O, u16* __restrict__ O2, int ldo,
            const float* __restrict__ bias, int K)
{
  constexpr int NFR = BN/32;
  __shared__ __align__(16) u16 sA[128*32];
  __shared__ __align__(16) u16 sB[BN*32];
  const int tid = threadIdx.x;
  const int m0 = blockIdx.x*128, n0 = blockIdx.y*BN;
  const int lane = tid & 63, wid = tid >> 6;
  const int wr = wid >> 1, wc = wid & 1;
  const int lr = lane & 15, g = lane >> 4;
  const f32x4 fz = {0.f,0.f,0.f,0.f};
  f32x4 acc[4][NFR];
  #pragma unroll
  for (int m=0;m<4;m++)
    #pragma unroll
    for (int n=0;n<NFR;n++) acc[m][n] = fz;
  const int nk = K >> 5;
  for (int kt = 0; kt < nk; ++kt){
    __syncthreads();
    #pragma unroll
    for (int i=0;i<2;i++){ int ci = i*256 + tid; int row = ci>>2, ko = (ci&3)*8;
      *(uint4*)(sA + row*32 + ko) = *(const uint4*)(A + (size_t)(m0+row)*lda + kt*32 + ko); }
    #pragma unroll
    for (int i=0;i<BN/64;i++){ int ci = i*256 + tid; int row = ci>>2, ko = (ci&3)*8;
      *(uint4*)(sB + row*32 + ko) = *(const uint4*)(Bw + (size_t)(n0+row)*ldb + kt*32 + ko); }
    __syncthreads();
    bfx8 af[4], bf[NFR];
    #pragma unroll
    for (int m=0;m<4;m++) af[m] = *(const bfx8*)(sA + (wr*64 + m*16 + lr)*32 + g*8);
    #pragma unroll
    for (int n=0;n<NFR;n++) bf[n] = *(const bfx8*)(sB + (wc*(BN/2) + n*16 + lr)*32 + g*8);
    #pragma unroll
    for (int m=0;m<4;m++)
      #pragma unroll
      for (int n=0;n<NFR;n++)
        acc[m][n] = __builtin_amdgcn_mfma_f32_16x16x32_bf16(af[m], bf[n], acc[m][n], 0, 0, 0);
  }
  #pragma unroll
  for (int m=0;m<4;m++)
    #pragma unroll
    for (int n=0;n<NFR;n++)
      #pragma unroll
      for (int r=0;r<4;r++){
        int row = m0 + wr*64 + m*16 + g*4 + r;
        int col = n0 + wc*(BN/2) + n*16 + lr;
        float v = acc[m][n][r];
        if (EPI == 0){
          O[(size_t)row*ldo + col] = f2b(v);
        } else if (EPI == 1){
          v += bias[col];
          v = (v > 20.f) ? v : log1pf(__expf(v));
          O[(size_t)row*ldo + col] = f2b(v);
        } else {
          if (col < 512) O[(size_t)row*512 + col] = f2b(v);
          else           O2[(size_t)row*512 + (col-512)] = f2b(v);
        }
      }
}

// ---------------- causal depthwise conv (k=4) + bias + silu -> u bf16 ----------------
__global__ __launch_bounds__(256)
void conv_k(const u16* __restrict__ xin, const float* __restrict__ cw,
            const float* __restrict__ cb, u16* __restrict__ u)
{
  const int t0 = blockIdx.x*32, d0 = blockIdx.y*64, b = blockIdx.z;
  const int tid = threadIdx.x;
  __shared__ float sx[35][64];
  __shared__ float sw[4][64];
  { int d = tid>>2, j = tid&3; sw[j][d] = cw[(d0+d)*4 + j]; }
  for (int i=0;i<9;i++){ int f = i*256 + tid; if (f < 35*64){
      int r = f>>6, dd = f&63; int t = t0 - 3 + r;
      sx[r][dd] = (t >= 0) ? b2f(xin[((size_t)(b*Tn)+t)*512 + d0+dd]) : 0.f; } }
  __syncthreads();
  const float cbv = cb[d0 + (tid&63)];
  for (int oi=0; oi<8; oi++){
    int f = oi*256 + tid; int tr = f>>6, dd = f&63;
    float a = cbv;
    #pragma unroll
    for (int j=0;j<4;j++) a += sw[j][dd]*sx[tr+j][dd];
    float sg = a/(1.f + __expf(-a));
    u[((size_t)(b*Tn)+t0+tr)*512 + d0+dd] = f2b(sg);
  }
}

// ---------------- scan pass A: per-chunk decay product P and zero-state carry c ----------------
__global__ __launch_bounds__(512)
void scanA_k(const u16* __restrict__ delta, const u16* __restrict__ u,
             const u16* __restrict__ dbl, const float* __restrict__ aL2,
             float* __restrict__ P, float* __restrict__ CC)
{
  const int ch = blockIdx.x, dt0 = blockIdx.y*32, b = blockIdx.z;
  const int tid = threadIdx.x, dl = tid>>4, n = tid&15, d = dt0+dl;
  const int t0 = ch*128;
  __shared__ float sD[128][32], sU[128][32], sB[128][16];
  for (int i=0;i<8;i++){ int f=i*512+tid; int t=f>>5, dd=f&31;
    size_t a = ((size_t)(b*Tn)+t0+t)*512 + dt0+dd;
    sD[t][dd] = b2f(delta[a]); sU[t][dd] = b2f(u[a]); }
  for (int i=0;i<4;i++){ int f=i*512+tid; int t=f>>4, nn=f&15;
    size_t a = ((size_t)(b*Tn)+t0+t)*64 + 32 + nn;
    sB[t][nn] = b2f(dbl[a]); }
  __syncthreads();
  const float aL = aL2[d*16+n];
  float h = 0.f, Pr = 1.f;
  for (int t=0;t<128;t++){
    float dlt = sD[t][dl], uu = sU[t][dl];
    float dA = exp2f(dlt*aL);
    h = fmaf(dA, h, (dlt*uu)*sB[t][n]);
    Pr *= dA;
  }
  size_t o = (((size_t)(b*64+ch))<<13) + (size_t)d*16 + n;
  P[o] = Pr; CC[o] = h;
}

// ---------------- scan pass B: sequential over chunks; P becomes h0 (exclusive) in place ----------------
__global__ __launch_bounds__(512)
void scanB_k(float* __restrict__ P, const float* __restrict__ CC)
{
  const int j = blockIdx.x, b = blockIdx.y;
  const int tid = threadIdx.x;
  const int d = j*32 + (tid>>4), n = tid&15;
  float h = 0.f;
  for (int ch=0; ch<64; ch++){
    size_t idx = (((size_t)(b*64+ch))<<13) + (size_t)d*16 + n;
    float Pv = P[idx], cv = CC[idx];
    P[idx] = h;                 // exclusive prefix -> h0
    h = fmaf(Pv, h, cv);
  }
}

// ---------------- scan pass C: recompute with h0, produce gated y' bf16 ----------------
__global__ __launch_bounds__(512)
void scanC_k(const u16* __restrict__ delta, const u16* __restrict__ u,
             const u16* __restrict__ dbl, const u16* __restrict__ z,
             const float* __restrict__ aL2, const float* __restrict__ h0,
             const float* __restrict__ Dp, u16* __restrict__ yg)
{
  const int ch = blockIdx.x, dt0 = blockIdx.y*32, b = blockIdx.z;
  const int tid = threadIdx.x, dl = tid>>4, n = tid&15, d = dt0+dl;
  const int t0 = ch*128;
  __shared__ float sD[128][32], sU[128][32], sB[128][16], sC[128][16];
  __shared__ u16 sZ[128][32], sY[128][32];
  for (int i=0;i<8;i++){ int f=i*512+tid; int t=f>>5, dd=f&31;
    size_t a = ((size_t)(b*Tn)+t0+t)*512 + dt0+dd;
    sD[t][dd] = b2f(delta[a]); sU[t][dd] = b2f(u[a]); sZ[t][dd] = z[a]; }
  for (int i=0;i<4;i++){ int f=i*512+tid; int t=f>>4, nn=f&15;
    size_t a = ((size_t)(b*Tn)+t0+t)*64 + nn;
    sB[t][nn] = b2f(dbl[a+32]); sC[t][nn] = b2f(dbl[a+48]); }
  __syncthreads();
  const float aL = aL2[d*16+n];
  const float Dd = Dp[d];
  size_t o = (((size_t)(b*64+ch))<<13) + (size_t)d*16 + n;
  float h = h0[o];
  for (int t=0;t<128;t++){
    float dlt = sD[t][dl], uu = sU[t][dl];
    float dA = exp2f(dlt*aL);
    h = fmaf(dA, h, (dlt*uu)*sB[t][n]);
    float p = h*sC[t][n];
    p += __shfl_xor(p,1); p += __shfl_xor(p,2); p += __shfl_xor(p,4); p += __shfl_xor(p,8);
    float zz = b2f(sZ[t][dl]);
    float gy = (p + uu*Dd) * (zz/(1.f + __expf(-zz)));
    if (n == 0) sY[t][dl] = f2b(gy);
  }
  __syncthreads();
  for (int i=0;i<8;i++){ int f=i*512+tid; int t=f>>5, dd=f&31;
    yg[((size_t)(b*Tn)+t0+t)*512 + dt0+dd] = sY[t][dd]; }
}

// ---------------- transpose (B,T,C)->(B,C,T) + residual, f32 out ----------------
__global__ __launch_bounds__(256)
void transres_k(const u16* __restrict__ yt, const float* __restrict__ x, float* __restrict__ out)
{
  const int t0 = blockIdx.x*64, c0 = blockIdx.y*64, b = blockIdx.z;
  const int tid = threadIdx.x;
  __shared__ float st[64][65];
  for (int i=0;i<16;i++){ int f=i*256+tid; int tr=f>>6, cc=f&63;
    st[tr][cc] = b2f(yt[((size_t)(b*Tn)+t0+tr)*256 + c0+cc]); }
  __syncthreads();
  for (int i=0;i<16;i++){ int f=i*256+tid; int cr=f>>6, tt=f&63;
    size_t oa = ((size_t)(b*256)+c0+cr)*Tn + t0+tt;
    out[oa] = st[tt][cr] + x[oa]; }
}

extern "C" void kernel_launch(void* const* d_in, const int* in_sizes, int n_in,
                              void* d_out, int out_size, void* d_ws, size_t ws_size,
                              hipStream_t stream)
{
  const float* x    = (const float*)d_in[0];
  const float* lnw  = (const float*)d_in[1];
  const float* lnb  = (const float*)d_in[2];
  const float* inw  = (const float*)d_in[3];
  const float* cw   = (const float*)d_in[4];
  const float* cb   = (const float*)d_in[5];
  const float* xpw  = (const float*)d_in[6];
  const float* dtw  = (const float*)d_in[7];
  const float* dtb  = (const float*)d_in[8];
  const float* alog = (const float*)d_in[9];
  const float* Dp   = (const float*)d_in[10];
  const float* opw  = (const float*)d_in[11];
  float* out = (float*)d_out;
  char* ws = (char*)d_ws;

  u16*   W     = (u16*)(ws + OFF_W);
  float* aL2   = (float*)(ws + OFF_AL2);
  u16*   xn    = (u16*)(ws + OFF_XN);
  u16*   xin   = (u16*)(ws + OFF_XIN);
  u16*   z     = (u16*)(ws + OFF_Z);
  u16*   u     = (u16*)(ws + OFF_U);
  u16*   dbl   = (u16*)(ws + OFF_DBL);
  u16*   delta = (u16*)(ws + OFF_DELTA);
  float* P     = (float*)(ws + OFF_P);
  float* CC    = (float*)(ws + OFF_CC);
  u16*   yg    = xin;   // x_in dead after conv
  u16*   ytmp  = xn;    // xn dead after GEMM1

  wconv_k<<<1760, 256, 0, stream>>>(inw, xpw, dtw, opw, alog, W, aL2);
  ln_k<<<dim3(Tn/64, Bn), 256, 0, stream>>>(x, lnw, lnb, xn);
  // in_proj: (32768x256) @ (1024x256)^T -> split x_in / z
  gemm_k<128,2><<<dim3(MTOT/128, 8), 256, 0, stream>>>(xn, 256, W, 256, xin, z, 512, nullptr, 256);
  conv_k<<<dim3(Tn/32, 8, Bn), 256, 0, stream>>>(xin, cw, cb, u);
  // x_proj (padded to N=64): u @ Wxpp^T -> dbl (dt|0|B|C)
  gemm_k<64,0><<<dim3(MTOT/128, 1), 256, 0, stream>>>(u, 512, W + 262144, 512, dbl, nullptr, 64, nullptr, 512);
  // dt_proj (K padded to 32) + softplus -> delta
  gemm_k<128,1><<<dim3(MTOT/128, 4), 256, 0, stream>>>(dbl, 64, W + 294912, 32, delta, nullptr, 512, dtb, 32);
  scanA_k<<<dim3(64, 16, Bn), 512, 0, stream>>>(delta, u, dbl, aL2, P, CC);
  scanB_k<<<dim3(16, Bn), 512, 0, stream>>>(P, CC);
  scanC_k<<<dim3(64, 16, Bn), 512, 0, stream>>>(delta, u, dbl, z, aL2, P, Dp, yg);
  // out_proj: yg @ Wop^T -> ytmp (B,T,256)
  gemm_k<128,0><<<dim3(MTOT/128, 2), 256, 0, stream>>>(yg, 512, W + 311296, 512, ytmp, nullptr, 256, nullptr, 512);
  transres_k<<<dim3(Tn/64, 4, Bn), 256, 0, stream>>>(ytmp, x, out);
}

// Round 2
// 375.467 us; speedup vs baseline: 1.5339x; 1.5339x over previous
//
#include <hip/hip_runtime.h>

typedef unsigned short u16;
typedef unsigned int u32;
typedef __bf16 bfx8 __attribute__((ext_vector_type(8)));
typedef float f32x4 __attribute__((ext_vector_type(4)));

#define Tn 8192
#define Bn 4
#define MTOT 32768
#define CH 128
#define TC 64

// ---- ws layout (bytes) ----
#define OFF_W     0ul
#define OFF_AL2   917504ul
#define OFF_XN    (1ul<<20)    // 16 MiB (reused as ytmp)
#define OFF_XIN   (17ul<<20)   // 32 MiB (reused as ygated)
#define OFF_Z     (49ul<<20)   // 32 MiB
#define OFF_U     (81ul<<20)   // 32 MiB
#define OFF_DBL   (113ul<<20)  // 4 MiB
#define OFF_DELTA (117ul<<20)  // 32 MiB
#define OFF_P     (149ul<<20)  // 16 MiB (becomes h0 after pass B)
#define OFF_CC    (165ul<<20)  // 16 MiB ; total 181 MiB

__device__ __forceinline__ float b2f(u16 h){ return __uint_as_float(((u32)h)<<16); }
__device__ __forceinline__ float bflo(u32 w){ return __uint_as_float(w<<16); }
__device__ __forceinline__ float bfhi(u32 w){ return __uint_as_float(w & 0xffff0000u); }
__device__ __forceinline__ u16 f2b(float f){
  u32 u = __float_as_uint(f);
  return (u16)((u + 0x7FFFu + ((u>>16)&1u)) >> 16);
}

// ---------------- weight convert / pad / A-table ----------------
__global__ void wconv_k(const float* __restrict__ inw, const float* __restrict__ xpw,
                        const float* __restrict__ dtw, const float* __restrict__ opw,
                        const float* __restrict__ alog, u16* __restrict__ W, float* __restrict__ aL2)
{
  int i = blockIdx.x*256 + threadIdx.x;
  if (i < 262144) { W[i] = f2b(inw[i]); return; }                       // in_proj (1024x256)
  if (i < 294912) { int j = i - 262144; int r = j >> 9, k = j & 511;    // x_proj padded (64x512)
    float v = (r < 16) ? xpw[r*512 + k] : ((r < 32) ? 0.f : xpw[(r-16)*512 + k]);
    W[i] = f2b(v); return; }
  if (i < 311296) { int j = i - 294912; int d = j >> 5, k = j & 31;     // dt_proj padded (512x32)
    W[i] = f2b((k < 16) ? dtw[d*16 + k] : 0.f); return; }
  if (i < 442368) { W[i] = f2b(opw[i - 311296]); return; }              // out_proj (256x512)
  if (i < 450560) { int j = i - 442368; aL2[j] = -__expf(alog[j]) * 1.44269504088896f; return; }
}

// ---------------- LayerNorm over C, write xn (B,T,C) bf16 ----------------
__global__ __launch_bounds__(256)
void ln_k(const float* __restrict__ x, const float* __restrict__ lnw,
          const float* __restrict__ lnb, u16* __restrict__ xn)
{
  const int t0 = blockIdx.x*64, b = blockIdx.y;
  const int tid = threadIdx.x, cg = tid>>6, tl = tid&63;
  __shared__ float ps[4][64], pq[4][64], mu[64], rs[64];
  float s = 0.f, q = 0.f;
  for (int ci = 0; ci < 64; ci++){
    int c = ci*4 + cg;
    float v = x[((size_t)(b*256 + c))*Tn + t0 + tl];
    s += v; q += v*v;
  }
  ps[cg][tl] = s; pq[cg][tl] = q;
  __syncthreads();
  if (tid < 64){
    float S = ps[0][tid]+ps[1][tid]+ps[2][tid]+ps[3][tid];
    float Q = pq[0][tid]+pq[1][tid]+pq[2][tid]+pq[3][tid];
    float m = S*(1.f/256.f);
    float var = Q*(1.f/256.f) - m*m;
    mu[tid] = m; rs[tid] = rsqrtf(var + 1e-5f);
  }
  __syncthreads();
  const float w = lnw[tid&255], bb = lnb[tid&255];
  for (int t = 0; t < 64; t++){
    float v = x[((size_t)(b*256 + tid))*Tn + t0 + t];
    xn[((size_t)(b*Tn) + t0 + t)*256 + tid] = f2b((v - mu[t])*rs[t]*w + bb);
  }
}

// ---------------- generic bf16 MFMA GEMM: out[m][n] = sum_k A[m][k]*Bw[n][k] ----------------
template<int BN, int EPI>
__global__ __launch_bounds__(256)
void gemm_k(const u16* __restrict__ A, int lda,
            const u16* __restrict__ Bw, int ldb,
            u16* __restrict__ O, u16* __restrict__ O2, int ldo,
            const float* __restrict__ bias, int K)
{
  constexpr int NFR = BN/32;
  __shared__ __align__(16) u16 sA[128*32];
  __shared__ __align__(16) u16 sB[BN*32];
  const int tid = threadIdx.x;
  const int m0 = blockIdx.x*128, n0 = blockIdx.y*BN;
  const int lane = tid & 63, wid = tid >> 6;
  const int wr = wid >> 1, wc = wid & 1;
  const int lr = lane & 15, g = lane >> 4;
  const f32x4 fz = {0.f,0.f,0.f,0.f};
  f32x4 acc[4][NFR];
  #pragma unroll
  for (int m=0;m<4;m++)
    #pragma unroll
    for (int n=0;n<NFR;n++) acc[m][n] = fz;
  const int nk = K >> 5;
  for (int kt = 0; kt < nk; ++kt){
    __syncthreads();
    #pragma unroll
    for (int i=0;i<2;i++){ int ci = i*256 + tid; int row = ci>>2, ko = (ci&3)*8;
      *(uint4*)(sA + row*32 + ko) = *(const uint4*)(A + (size_t)(m0+row)*lda + kt*32 + ko); }
    #pragma unroll
    for (int i=0;i<BN/64;i++){ int ci = i*256 + tid; int row = ci>>2, ko = (ci&3)*8;
      *(uint4*)(sB + row*32 + ko) = *(const uint4*)(Bw + (size_t)(n0+row)*ldb + kt*32 + ko); }
    __syncthreads();
    bfx8 af[4], bf[NFR];
    #pragma unroll
    for (int m=0;m<4;m++) af[m] = *(const bfx8*)(sA + (wr*64 + m*16 + lr)*32 + g*8);
    #pragma unroll
    for (int n=0;n<NFR;n++) bf[n] = *(const bfx8*)(sB + (wc*(BN/2) + n*16 + lr)*32 + g*8);
    #pragma unroll
    for (int m=0;m<4;m++)
      #pragma unroll
      for (int n=0;n<NFR;n++)
        acc[m][n] = __builtin_amdgcn_mfma_f32_16x16x32_bf16(af[m], bf[n], acc[m][n], 0, 0, 0);
  }
  #pragma unroll
  for (int m=0;m<4;m++)
    #pragma unroll
    for (int n=0;n<NFR;n++)
      #pragma unroll
      for (int r=0;r<4;r++){
        int row = m0 + wr*64 + m*16 + g*4 + r;
        int col = n0 + wc*(BN/2) + n*16 + lr;
        float v = acc[m][n][r];
        if (EPI == 0){
          O[(size_t)row*ldo + col] = f2b(v);
        } else if (EPI == 1){
          v += bias[col];
          v = (v > 20.f) ? v : log1pf(__expf(v));
          O[(size_t)row*ldo + col] = f2b(v);
        } else {
          if (col < 512) O[(size_t)row*512 + col] = f2b(v);
          else           O2[(size_t)row*512 + (col-512)] = f2b(v);
        }
      }
}

// ---------------- causal depthwise conv (k=4) + bias + silu -> u bf16 ----------------
__global__ __launch_bounds__(256)
void conv_k(const u16* __restrict__ xin, const float* __restrict__ cw,
            const float* __restrict__ cb, u16* __restrict__ u)
{
  const int t0 = blockIdx.x*32, d0 = blockIdx.y*64, b = blockIdx.z;
  const int tid = threadIdx.x;
  __shared__ float sx[35][64];
  __shared__ float sw[4][64];
  { int d = tid>>2, j = tid&3; sw[j][d] = cw[(d0+d)*4 + j]; }
  for (int i=0;i<9;i++){ int f = i*256 + tid; if (f < 35*64){
      int r = f>>6, dd = f&63; int t = t0 - 3 + r;
      sx[r][dd] = (t >= 0) ? b2f(xin[((size_t)(b*Tn)+t)*512 + d0+dd]) : 0.f; } }
  __syncthreads();
  const float cbv = cb[d0 + (tid&63)];
  for (int oi=0; oi<8; oi++){
    int f = oi*256 + tid; int tr = f>>6, dd = f&63;
    float a = cbv;
    #pragma unroll
    for (int j=0;j<4;j++) a += sw[j][dd]*sx[tr+j][dd];
    float sg = a/(1.f + __expf(-a));
    u[((size_t)(b*Tn)+t0+tr)*512 + d0+dd] = f2b(sg);
  }
}

// ---------------- scan pass A: thread-per-d, h[16] in regs; chunk decay P + zero-state carry c ----------------
__global__ __launch_bounds__(256)
void scanA_k(const u16* __restrict__ delta, const u16* __restrict__ u,
             const u16* __restrict__ dbl, const float* __restrict__ aL2,
             float* __restrict__ P, float* __restrict__ CC)
{
  const int ch = blockIdx.x, d = blockIdx.y*256 + threadIdx.x, b = blockIdx.z;
  const int t0 = ch*TC;
  float aL[16], h[16], Pq[16];
  #pragma unroll
  for (int i=0;i<4;i++) *(f32x4*)(aL+4*i) = *(const f32x4*)(aL2 + (size_t)d*16 + 4*i);
  #pragma unroll
  for (int n=0;n<16;n++){ h[n]=0.f; Pq[n]=1.f; }
  const u16* dp = delta + (size_t)(b*Tn + t0)*512 + d;
  const u16* up = u     + (size_t)(b*Tn + t0)*512 + d;
  const u16* bp = dbl   + (size_t)(b*Tn + t0)*64 + 32;
  for (int t=0;t<TC;t++){
    float dlt = b2f(dp[(size_t)t*512]);
    float uu  = b2f(up[(size_t)t*512]);
    uint4 bv0 = *(const uint4*)(bp + (size_t)t*64);
    uint4 bv1 = *(const uint4*)(bp + (size_t)t*64 + 8);
    float du = dlt*uu;
    float Bv[16];
    u32 w0[4] = {bv0.x,bv0.y,bv0.z,bv0.w};
    u32 w1[4] = {bv1.x,bv1.y,bv1.z,bv1.w};
    #pragma unroll
    for (int j=0;j<4;j++){
      Bv[2*j]   = bflo(w0[j]); Bv[2*j+1] = bfhi(w0[j]);
      Bv[8+2*j] = bflo(w1[j]); Bv[9+2*j] = bfhi(w1[j]);
    }
    #pragma unroll
    for (int n=0;n<16;n++){
      float e = exp2f(dlt*aL[n]);
      h[n] = fmaf(e, h[n], du*Bv[n]);
      Pq[n] *= e;
    }
  }
  size_t o = ((size_t)((b*CH+ch)*512 + d))<<4;
  #pragma unroll
  for (int i=0;i<4;i++){
    *(f32x4*)(P +o+4*i) = *(f32x4*)(Pq+4*i);
    *(f32x4*)(CC+o+4*i) = *(f32x4*)(h +4*i);
  }
}

// ---------------- scan pass B: sequential over chunks; P becomes h0 (exclusive) in place ----------------
__global__ __launch_bounds__(256)
void scanB_k(float* __restrict__ P, const float* __restrict__ CC)
{
  const int gid = blockIdx.x*256 + threadIdx.x;   // 8192 threads: (b, d, n4)
  const int b = gid >> 11, r = gid & 2047;
  const size_t base = (size_t)(r>>2)*16 + (size_t)(r&3)*4;
  f32x4 h = {0.f,0.f,0.f,0.f};
  #pragma unroll 4
  for (int ch=0; ch<CH; ch++){
    size_t idx = ((size_t)(b*CH+ch))*8192 + base;
    f32x4 Pv = *(f32x4*)(P+idx);
    f32x4 cv = *(const f32x4*)(CC+idx);
    *(f32x4*)(P+idx) = h;                 // exclusive prefix -> h0
    h = Pv*h + cv;
  }
}

// ---------------- scan pass C: recompute with h0, produce gated y' bf16 ----------------
__global__ __launch_bounds__(256)
void scanC_k(const u16* __restrict__ delta, const u16* __restrict__ u,
             const u16* __restrict__ dbl, const u16* __restrict__ z,
             const float* __restrict__ aL2, const float* __restrict__ h0,
             const float* __restrict__ Dp, u16* __restrict__ yg)
{
  const int ch = blockIdx.x, d = blockIdx.y*256 + threadIdx.x, b = blockIdx.z;
  const int t0 = ch*TC;
  float aL[16], h[16];
  #pragma unroll
  for (int i=0;i<4;i++) *(f32x4*)(aL+4*i) = *(const f32x4*)(aL2 + (size_t)d*16 + 4*i);
  size_t o = ((size_t)((b*CH+ch)*512 + d))<<4;
  #pragma unroll
  for (int i=0;i<4;i++) *(f32x4*)(h+4*i) = *(const f32x4*)(h0+o+4*i);
  const float Dd = Dp[d];
  const u16* dp = delta + (size_t)(b*Tn + t0)*512 + d;
  const u16* up = u     + (size_t)(b*Tn + t0)*512 + d;
  const u16* zp = z     + (size_t)(b*Tn + t0)*512 + d;
  const u16* bp = dbl   + (size_t)(b*Tn + t0)*64 + 32;
  u16* yp = yg + (size_t)(b*Tn + t0)*512 + d;
  for (int t=0;t<TC;t++){
    float dlt = b2f(dp[(size_t)t*512]);
    float uu  = b2f(up[(size_t)t*512]);
    float zz  = b2f(zp[(size_t)t*512]);
    uint4 bv0 = *(const uint4*)(bp + (size_t)t*64);
    uint4 bv1 = *(const uint4*)(bp + (size_t)t*64 + 8);
    uint4 cv0 = *(const uint4*)(bp + (size_t)t*64 + 16);
    uint4 cv1 = *(const uint4*)(bp + (size_t)t*64 + 24);
    float du = dlt*uu;
    float Bv[16], Cv[16];
    u32 w0[4] = {bv0.x,bv0.y,bv0.z,bv0.w};
    u32 w1[4] = {bv1.x,bv1.y,bv1.z,bv1.w};
    u32 w2[4] = {cv0.x,cv0.y,cv0.z,cv0.w};
    u32 w3[4] = {cv1.x,cv1.y,cv1.z,cv1.w};
    #pragma unroll
    for (int j=0;j<4;j++){
      Bv[2*j]   = bflo(w0[j]); Bv[2*j+1] = bfhi(w0[j]);
      Bv[8+2*j] = bflo(w1[j]); Bv[9+2*j] = bfhi(w1[j]);
      Cv[2*j]   = bflo(w2[j]); Cv[2*j+1] = bfhi(w2[j]);
      Cv[8+2*j] = bflo(w3[j]); Cv[9+2*j] = bfhi(w3[j]);
    }
    float p0=0.f, p1=0.f, p2=0.f, p3=0.f;
    #pragma unroll
    for (int n=0;n<16;n+=4){
      float e0 = exp2f(dlt*aL[n]),   e1 = exp2f(dlt*aL[n+1]);
      float e2 = exp2f(dlt*aL[n+2]), e3 = exp2f(dlt*aL[n+3]);
      h[n]   = fmaf(e0, h[n],   du*Bv[n]);   p0 = fmaf(h[n],   Cv[n],   p0);
      h[n+1] = fmaf(e1, h[n+1], du*Bv[n+1]); p1 = fmaf(h[n+1], Cv[n+1], p1);
      h[n+2] = fmaf(e2, h[n+2], du*Bv[n+2]); p2 = fmaf(h[n+2], Cv[n+2], p2);
      h[n+3] = fmaf(e3, h[n+3], du*Bv[n+3]); p3 = fmaf(h[n+3], Cv[n+3], p3);
    }
    float p = (p0+p1) + (p2+p3);
    float sg = zz/(1.f + __expf(-zz));
    float gy = (p + uu*Dd) * sg;
    yp[(size_t)t*512] = f2b(gy);
  }
}

// ---------------- transpose (B,T,C)->(B,C,T) + residual, f32 out ----------------
__global__ __launch_bounds__(256)
void transres_k(const u16* __restrict__ yt, const float* __restrict__ x, float* __restrict__ out)
{
  const int t0 = blockIdx.x*64, c0 = blockIdx.y*64, b = blockIdx.z;
  const int tid = threadIdx.x;
  __shared__ float st[64][65];
  for (int i=0;i<16;i++){ int f=i*256+tid; int tr=f>>6, cc=f&63;
    st[tr][cc] = b2f(yt[((size_t)(b*Tn)+t0+tr)*256 + c0+cc]); }
  __syncthreads();
  for (int i=0;i<16;i++){ int f=i*256+tid; int cr=f>>6, tt=f&63;
    size_t oa = ((size_t)(b*256)+c0+cr)*Tn + t0+tt;
    out[oa] = st[tt][cr] + x[oa]; }
}

extern "C" void kernel_launch(void* const* d_in, const int* in_sizes, int n_in,
                              void* d_out, int out_size, void* d_ws, size_t ws_size,
                              hipStream_t stream)
{
  const float* x    = (const float*)d_in[0];
  const float* lnw  = (const float*)d_in[1];
  const float* lnb  = (const float*)d_in[2];
  const float* inw  = (const float*)d_in[3];
  const float* cw   = (const float*)d_in[4];
  const float* cb   = (const float*)d_in[5];
  const float* xpw  = (const float*)d_in[6];
  const float* dtw  = (const float*)d_in[7];
  const float* dtb  = (const float*)d_in[8];
  const float* alog = (const float*)d_in[9];
  const float* Dp   = (const float*)d_in[10];
  const float* opw  = (const float*)d_in[11];
  float* out = (float*)d_out;
  char* ws = (char*)d_ws;

  u16*   W     = (u16*)(ws + OFF_W);
  float* aL2   = (float*)(ws + OFF_AL2);
  u16*   xn    = (u16*)(ws + OFF_XN);
  u16*   xin   = (u16*)(ws + OFF_XIN);
  u16*   z     = (u16*)(ws + OFF_Z);
  u16*   u     = (u16*)(ws + OFF_U);
  u16*   dbl   = (u16*)(ws + OFF_DBL);
  u16*   delta = (u16*)(ws + OFF_DELTA);
  float* P     = (float*)(ws + OFF_P);
  float* CC    = (float*)(ws + OFF_CC);
  u16*   yg    = xin;   // x_in dead after conv
  u16*   ytmp  = xn;    // xn dead after GEMM1

  wconv_k<<<1760, 256, 0, stream>>>(inw, xpw, dtw, opw, alog, W, aL2);
  ln_k<<<dim3(Tn/64, Bn), 256, 0, stream>>>(x, lnw, lnb, xn);
  // in_proj: (32768x256) @ (1024x256)^T -> split x_in / z
  gemm_k<128,2><<<dim3(MTOT/128, 8), 256, 0, stream>>>(xn, 256, W, 256, xin, z, 512, nullptr, 256);
  conv_k<<<dim3(Tn/32, 8, Bn), 256, 0, stream>>>(xin, cw, cb, u);
  // x_proj (padded to N=64): u @ Wxpp^T -> dbl (dt|0|B|C)
  gemm_k<64,0><<<dim3(MTOT/128, 1), 256, 0, stream>>>(u, 512, W + 262144, 512, dbl, nullptr, 64, nullptr, 512);
  // dt_proj (K padded to 32) + softplus -> delta
  gemm_k<128,1><<<dim3(MTOT/128, 4), 256, 0, stream>>>(dbl, 64, W + 294912, 32, delta, nullptr, 512, dtb, 32);
  scanA_k<<<dim3(CH, 2, Bn), 256, 0, stream>>>(delta, u, dbl, aL2, P, CC);
  scanB_k<<<32, 256, 0, stream>>>(P, CC);
  scanC_k<<<dim3(CH, 2, Bn), 256, 0, stream>>>(delta, u, dbl, z, aL2, P, Dp, yg);
  // out_proj: yg @ Wop^T -> ytmp (B,T,256)
  gemm_k<128,0><<<dim3(MTOT/128, 2), 256, 0, stream>>>(yg, 512, W + 311296, 512, ytmp, nullptr, 256, nullptr, 512);
  transres_k<<<dim3(Tn/64, 4, Bn), 256, 0, stream>>>(ytmp, x, out);
}

// Round 3
// 230.320 us; speedup vs baseline: 2.5005x; 1.6302x over previous
//
#include <hip/hip_runtime.h>

typedef unsigned short u16;
typedef unsigned int u32;
typedef __bf16 bfx8 __attribute__((ext_vector_type(8)));
typedef float f32x4 __attribute__((ext_vector_type(4)));

#define Tn 8192
#define Bn 4
#define MTOT 32768
#define CH 128
#define TC 64

// ---- ws layout (bytes) ----
#define OFF_W     0ul
#define OFF_AL2   917504ul
#define OFF_XN    (1ul<<20)    // 16 MiB (reused as ytmp)
#define OFF_XIN   (17ul<<20)   // 32 MiB (reused as ygated)
#define OFF_Z     (49ul<<20)   // 32 MiB
#define OFF_U     (81ul<<20)   // 32 MiB
#define OFF_DBLDT (113ul<<20)  // 2 MiB  (dt | pad, 32 u16/row)
#define OFF_BCF   (115ul<<20)  // 4 MiB  (B|C f32, 32 f32/row)
#define OFF_DELTA (119ul<<20)  // 32 MiB
#define OFF_P     (151ul<<20)  // 16 MiB (becomes h0 after pass B)
#define OFF_CC    (167ul<<20)  // 16 MiB ; total 183 MiB

__device__ __forceinline__ float b2f(u16 h){ return __uint_as_float(((u32)h)<<16); }
__device__ __forceinline__ u16 f2b(float f){
  u32 u = __float_as_uint(f);
  return (u16)((u + 0x7FFFu + ((u>>16)&1u)) >> 16);
}
__device__ __forceinline__ float aexp2(float x){ float r; asm("v_exp_f32 %0, %1" : "=v"(r) : "v"(x)); return r; }
__device__ __forceinline__ float arcp (float x){ float r; asm("v_rcp_f32 %0, %1" : "=v"(r) : "v"(x)); return r; }
__device__ __forceinline__ float alog2(float x){ float r; asm("v_log_f32 %0, %1" : "=v"(r) : "v"(x)); return r; }
__device__ __forceinline__ float fsilu(float a){ return a*arcp(1.f + aexp2(-a*1.44269504f)); }
__device__ __forceinline__ float fsoftplus(float v){
  float r = 0.69314718f*alog2(1.f + aexp2(v*1.44269504f));
  return (v > 20.f) ? v : r;
}
typedef const __attribute__((address_space(1))) void* gp1_t;
typedef __attribute__((address_space(3))) void* lp3_t;
__device__ __forceinline__ void gload_lds16(const void* g, void* l){
  __builtin_amdgcn_global_load_lds((gp1_t)g, (lp3_t)l, 16, 0, 0);
}

// ---------------- weight convert / pad / A-table ----------------
__global__ void wconv_k(const float* __restrict__ inw, const float* __restrict__ xpw,
                        const float* __restrict__ dtw, const float* __restrict__ opw,
                        const float* __restrict__ alog, u16* __restrict__ W, float* __restrict__ aL2)
{
  int i = blockIdx.x*256 + threadIdx.x;
  if (i < 262144) { W[i] = f2b(inw[i]); return; }                       // in_proj (1024x256)
  if (i < 294912) { int j = i - 262144; int r = j >> 9, k = j & 511;    // x_proj padded (64x512)
    float v = (r < 16) ? xpw[r*512 + k] : ((r < 32) ? 0.f : xpw[(r-16)*512 + k]);
    W[i] = f2b(v); return; }
  if (i < 311296) { int j = i - 294912; int d = j >> 5, k = j & 31;     // dt_proj padded (512x32)
    W[i] = f2b((k < 16) ? dtw[d*16 + k] : 0.f); return; }
  if (i < 442368) { W[i] = f2b(opw[i - 311296]); return; }              // out_proj (256x512)
  if (i < 450560) { int j = i - 442368; aL2[j] = -__expf(alog[j]) * 1.44269504088896f; return; }
}

// ---------------- LayerNorm over C, write xn (B,T,C) bf16 ----------------
__global__ __launch_bounds__(256)
void ln_k(const float* __restrict__ x, const float* __restrict__ lnw,
          const float* __restrict__ lnb, u16* __restrict__ xn)
{
  const int t0 = blockIdx.x*64, b = blockIdx.y;
  const int tid = threadIdx.x, cg = tid>>6, tl = tid&63;
  __shared__ float ps[4][64], pq[4][64], mu[64], rs[64];
  float s = 0.f, q = 0.f;
  for (int ci = 0; ci < 64; ci++){
    int c = ci*4 + cg;
    float v = x[((size_t)(b*256 + c))*Tn + t0 + tl];
    s += v; q += v*v;
  }
  ps[cg][tl] = s; pq[cg][tl] = q;
  __syncthreads();
  if (tid < 64){
    float S = ps[0][tid]+ps[1][tid]+ps[2][tid]+ps[3][tid];
    float Q = pq[0][tid]+pq[1][tid]+pq[2][tid]+pq[3][tid];
    float m = S*(1.f/256.f);
    float var = Q*(1.f/256.f) - m*m;
    mu[tid] = m; rs[tid] = rsqrtf(var + 1e-5f);
  }
  __syncthreads();
  const float w = lnw[tid&255], bb = lnb[tid&255];
  for (int t = 0; t < 64; t++){
    float v = x[((size_t)(b*256 + tid))*Tn + t0 + t];
    xn[((size_t)(b*Tn) + t0 + t)*256 + tid] = f2b((v - mu[t])*rs[t]*w + bb);
  }
}

// ---------------- generic bf16 MFMA GEMM: out[m][n] = sum_k A[m][k]*Bw[n][k] ----------------
// EPI 0: bf16 ; 1: softplus(v+bias[n]) bf16 ; 2: split col<512->O else O2 ; 3: col<32->O bf16 else Of f32
template<int BN, int EPI>
__global__ __launch_bounds__(256)
void gemm_k(const u16* __restrict__ A, int lda,
            const u16* __restrict__ Bw, int ldb,
            u16* __restrict__ O, u16* __restrict__ O2, float* __restrict__ Of, int ldo,
            const float* __restrict__ bias, int K)
{
  constexpr int NFR = BN/32;
  __shared__ __align__(16) u16 sA[128*32];
  __shared__ __align__(16) u16 sB[BN*32];
  const int tid = threadIdx.x;
  const int m0 = blockIdx.x*128, n0 = blockIdx.y*BN;
  const int lane = tid & 63, wid = tid >> 6;
  const int wr = wid >> 1, wc = wid & 1;
  const int lr = lane & 15, g = lane >> 4;
  const f32x4 fz = {0.f,0.f,0.f,0.f};
  f32x4 acc[4][NFR];
  #pragma unroll
  for (int m=0;m<4;m++)
    #pragma unroll
    for (int n=0;n<NFR;n++) acc[m][n] = fz;
  const int nk = K >> 5;
  for (int kt = 0; kt < nk; ++kt){
    __syncthreads();
    #pragma unroll
    for (int i=0;i<2;i++){ int ci = i*256 + tid;
      gload_lds16(A + (size_t)(m0+(ci>>2))*lda + kt*32 + (ci&3)*8, sA + ci*8); }
    #pragma unroll
    for (int i=0;i<BN/64;i++){ int ci = i*256 + tid;
      gload_lds16(Bw + (size_t)(n0+(ci>>2))*ldb + kt*32 + (ci&3)*8, sB + ci*8); }
    __syncthreads();
    bfx8 af[4], bf[NFR];
    #pragma unroll
    for (int m=0;m<4;m++) af[m] = *(const bfx8*)(sA + (wr*64 + m*16 + lr)*32 + g*8);
    #pragma unroll
    for (int n=0;n<NFR;n++) bf[n] = *(const bfx8*)(sB + (wc*(BN/2) + n*16 + lr)*32 + g*8);
    #pragma unroll
    for (int m=0;m<4;m++)
      #pragma unroll
      for (int n=0;n<NFR;n++)
        acc[m][n] = __builtin_amdgcn_mfma_f32_16x16x32_bf16(af[m], bf[n], acc[m][n], 0, 0, 0);
  }
  #pragma unroll
  for (int m=0;m<4;m++)
    #pragma unroll
    for (int n=0;n<NFR;n++)
      #pragma unroll
      for (int r=0;r<4;r++){
        int row = m0 + wr*64 + m*16 + g*4 + r;
        int col = n0 + wc*(BN/2) + n*16 + lr;
        float v = acc[m][n][r];
        if (EPI == 0){
          O[(size_t)row*ldo + col] = f2b(v);
        } else if (EPI == 1){
          O[(size_t)row*ldo + col] = f2b(fsoftplus(v + bias[col]));
        } else if (EPI == 2){
          if (col < 512) O[(size_t)row*512 + col] = f2b(v);
          else           O2[(size_t)row*512 + (col-512)] = f2b(v);
        } else {
          if (col < 32) O[(size_t)row*32 + col] = f2b(v);
          else          Of[(size_t)row*32 + (col-32)] = v;
        }
      }
}

// ---------------- causal depthwise conv (k=4) + bias + silu -> u bf16 ----------------
__global__ __launch_bounds__(256)
void conv_k(const u16* __restrict__ xin, const float* __restrict__ cw,
            const float* __restrict__ cb, u16* __restrict__ u)
{
  const int t0 = blockIdx.x*32, d0 = blockIdx.y*64, b = blockIdx.z;
  const int tid = threadIdx.x;
  __shared__ float sx[35][64];
  __shared__ float sw[4][64];
  { int d = tid>>2, j = tid&3; sw[j][d] = cw[(d0+d)*4 + j]; }
  for (int i=0;i<9;i++){ int f = i*256 + tid; if (f < 35*64){
      int r = f>>6, dd = f&63; int t = t0 - 3 + r;
      sx[r][dd] = (t >= 0) ? b2f(xin[((size_t)(b*Tn)+t)*512 + d0+dd]) : 0.f; } }
  __syncthreads();
  const float cbv = cb[d0 + (tid&63)];
  for (int oi=0; oi<8; oi++){
    int f = oi*256 + tid; int tr = f>>6, dd = f&63;
    float a = cbv;
    #pragma unroll
    for (int j=0;j<4;j++) a += sw[j][dd]*sx[tr+j][dd];
    u[((size_t)(b*Tn)+t0+tr)*512 + d0+dd] = f2b(fsilu(a));
  }
}

// ---------------- scan pass A: thread-per-d, h[16] in regs ----------------
__global__ __launch_bounds__(256)
void scanA_k(const u16* __restrict__ delta, const u16* __restrict__ u,
             const float* __restrict__ bcf, const float* __restrict__ aL2,
             float* __restrict__ P, float* __restrict__ CC)
{
  const int ch = blockIdx.x, d = blockIdx.y*256 + threadIdx.x, b = blockIdx.z;
  const int t0 = ch*TC;
  float aL[16], h[16];
  #pragma unroll
  for (int i=0;i<4;i++) *(f32x4*)(aL+4*i) = *(const f32x4*)(aL2 + (size_t)d*16 + 4*i);
  #pragma unroll
  for (int n=0;n<16;n++) h[n] = 0.f;
  bool st = true;
  #pragma unroll
  for (int n=1;n<16;n++) st = st && (fabsf(aL[n] - (n+1)*aL[0]) <= 2e-4f*fabsf(aL[n]));
  const u16* dp = delta + (size_t)(b*Tn + t0)*512 + d;
  const u16* up = u     + (size_t)(b*Tn + t0)*512 + d;
  const float* bp = bcf + (size_t)(b*Tn + t0)*32;
  float sdlt = 0.f;
  const float aL0 = aL[0];
  if (st){
    for (int t=0;t<TC;t++){
      float dlt = b2f(dp[(size_t)t*512]);
      float uu  = b2f(up[(size_t)t*512]);
      float Bv[16];
      #pragma unroll
      for (int i=0;i<4;i++) *(f32x4*)(Bv+4*i) = *(const f32x4*)(bp + (size_t)t*32 + 4*i);
      float du = dlt*uu; sdlt += dlt;
      float r = aexp2(dlt*aL0);
      float r2 = r*r, e = r, f = r2;
      #pragma unroll
      for (int n=0;n<16;n+=2){
        h[n]   = fmaf(e, h[n],   du*Bv[n]);
        h[n+1] = fmaf(f, h[n+1], du*Bv[n+1]);
        e *= r2; f *= r2;
      }
    }
  } else {
    for (int t=0;t<TC;t++){
      float dlt = b2f(dp[(size_t)t*512]);
      float uu  = b2f(up[(size_t)t*512]);
      float Bv[16];
      #pragma unroll
      for (int i=0;i<4;i++) *(f32x4*)(Bv+4*i) = *(const f32x4*)(bp + (size_t)t*32 + 4*i);
      float du = dlt*uu; sdlt += dlt;
      #pragma unroll
      for (int n=0;n<16;n++)
        h[n] = fmaf(aexp2(dlt*aL[n]), h[n], du*Bv[n]);
    }
  }
  float Pq[16];
  #pragma unroll
  for (int n=0;n<16;n++) Pq[n] = aexp2(sdlt*aL[n]);
  size_t o = ((size_t)((b*CH+ch)*512 + d))<<4;
  #pragma unroll
  for (int i=0;i<4;i++){
    *(f32x4*)(P +o+4*i) = *(f32x4*)(Pq+4*i);
    *(f32x4*)(CC+o+4*i) = *(f32x4*)(h +4*i);
  }
}

// ---------------- scan pass B: sequential over chunks; P becomes h0 (exclusive) in place ----------------
__global__ __launch_bounds__(256)
void scanB_k(float* __restrict__ P, const float* __restrict__ CC)
{
  const int gid = blockIdx.x*256 + threadIdx.x;   // 8192 threads: (b, d, n4)
  const int b = gid >> 11, r = gid & 2047;
  const size_t base = (size_t)(r>>2)*16 + (size_t)(r&3)*4;
  f32x4 h = {0.f,0.f,0.f,0.f};
  #pragma unroll 4
  for (int ch=0; ch<CH; ch++){
    size_t idx = ((size_t)(b*CH+ch))*8192 + base;
    f32x4 Pv = *(f32x4*)(P+idx);
    f32x4 cv = *(const f32x4*)(CC+idx);
    *(f32x4*)(P+idx) = h;                 // exclusive prefix -> h0
    h = Pv*h + cv;
  }
}

// ---------------- scan pass C: recompute with h0, produce gated y' bf16 ----------------
__global__ __launch_bounds__(256)
void scanC_k(const u16* __restrict__ delta, const u16* __restrict__ u,
             const float* __restrict__ bcf, const u16* __restrict__ z,
             const float* __restrict__ aL2, const float* __restrict__ h0,
             const float* __restrict__ Dp, u16* __restrict__ yg)
{
  const int ch = blockIdx.x, d = blockIdx.y*256 + threadIdx.x, b = blockIdx.z;
  const int t0 = ch*TC;
  float aL[16], h[16];
  #pragma unroll
  for (int i=0;i<4;i++) *(f32x4*)(aL+4*i) = *(const f32x4*)(aL2 + (size_t)d*16 + 4*i);
  size_t o = ((size_t)((b*CH+ch)*512 + d))<<4;
  #pragma unroll
  for (int i=0;i<4;i++) *(f32x4*)(h+4*i) = *(const f32x4*)(h0+o+4*i);
  bool st = true;
  #pragma unroll
  for (int n=1;n<16;n++) st = st && (fabsf(aL[n] - (n+1)*aL[0]) <= 2e-4f*fabsf(aL[n]));
  const float Dd = Dp[d];
  const float aL0 = aL[0];
  const u16* dp = delta + (size_t)(b*Tn + t0)*512 + d;
  const u16* up = u     + (size_t)(b*Tn + t0)*512 + d;
  const u16* zp = z     + (size_t)(b*Tn + t0)*512 + d;
  const float* bp = bcf + (size_t)(b*Tn + t0)*32;
  u16* yp = yg + (size_t)(b*Tn + t0)*512 + d;
  if (st){
    for (int t=0;t<TC;t++){
      float dlt = b2f(dp[(size_t)t*512]);
      float uu  = b2f(up[(size_t)t*512]);
      float zz  = b2f(zp[(size_t)t*512]);
      float Bv[16], Cv[16];
      #pragma unroll
      for (int i=0;i<4;i++){
        *(f32x4*)(Bv+4*i) = *(const f32x4*)(bp + (size_t)t*32 + 4*i);
        *(f32x4*)(Cv+4*i) = *(const f32x4*)(bp + (size_t)t*32 + 16 + 4*i);
      }
      float du = dlt*uu;
      float r = aexp2(dlt*aL0);
      float r2 = r*r, e = r, f = r2;
      float p0=0.f, p1=0.f;
      #pragma unroll
      for (int n=0;n<16;n+=2){
        h[n]   = fmaf(e, h[n],   du*Bv[n]);   p0 = fmaf(h[n],   Cv[n],   p0);
        h[n+1] = fmaf(f, h[n+1], du*Bv[n+1]); p1 = fmaf(h[n+1], Cv[n+1], p1);
        e *= r2; f *= r2;
      }
      float p = p0 + p1;
      float gy = (p + uu*Dd) * fsilu(zz);
      yp[(size_t)t*512] = f2b(gy);
    }
  } else {
    for (int t=0;t<TC;t++){
      float dlt = b2f(dp[(size_t)t*512]);
      float uu  = b2f(up[(size_t)t*512]);
      float zz  = b2f(zp[(size_t)t*512]);
      float Bv[16], Cv[16];
      #pragma unroll
      for (int i=0;i<4;i++){
        *(f32x4*)(Bv+4*i) = *(const f32x4*)(bp + (size_t)t*32 + 4*i);
        *(f32x4*)(Cv+4*i) = *(const f32x4*)(bp + (size_t)t*32 + 16 + 4*i);
      }
      float du = dlt*uu;
      float p0 = 0.f;
      #pragma unroll
      for (int n=0;n<16;n++){
        h[n] = fmaf(aexp2(dlt*aL[n]), h[n], du*Bv[n]);
        p0 = fmaf(h[n], Cv[n], p0);
      }
      float gy = (p0 + uu*Dd) * fsilu(zz);
      yp[(size_t)t*512] = f2b(gy);
    }
  }
}

// ---------------- transpose (B,T,C)->(B,C,T) + residual, f32 out ----------------
__global__ __launch_bounds__(256)
void transres_k(const u16* __restrict__ yt, const float* __restrict__ x, float* __restrict__ out)
{
  const int t0 = blockIdx.x*64, c0 = blockIdx.y*64, b = blockIdx.z;
  const int tid = threadIdx.x;
  __shared__ float st[64][65];
  for (int i=0;i<16;i++){ int f=i*256+tid; int tr=f>>6, cc=f&63;
    st[tr][cc] = b2f(yt[((size_t)(b*Tn)+t0+tr)*256 + c0+cc]); }
  __syncthreads();
  for (int i=0;i<16;i++){ int f=i*256+tid; int cr=f>>6, tt=f&63;
    size_t oa = ((size_t)(b*256)+c0+cr)*Tn + t0+tt;
    out[oa] = st[tt][cr] + x[oa]; }
}

extern "C" void kernel_launch(void* const* d_in, const int* in_sizes, int n_in,
                              void* d_out, int out_size, void* d_ws, size_t ws_size,
                              hipStream_t stream)
{
  const float* x    = (const float*)d_in[0];
  const float* lnw  = (const float*)d_in[1];
  const float* lnb  = (const float*)d_in[2];
  const float* inw  = (const float*)d_in[3];
  const float* cw   = (const float*)d_in[4];
  const float* cb   = (const float*)d_in[5];
  const float* xpw  = (const float*)d_in[6];
  const float* dtw  = (const float*)d_in[7];
  const float* dtb  = (const float*)d_in[8];
  const float* alog = (const float*)d_in[9];
  const float* Dp   = (const float*)d_in[10];
  const float* opw  = (const float*)d_in[11];
  float* out = (float*)d_out;
  char* ws = (char*)d_ws;

  u16*   W     = (u16*)(ws + OFF_W);
  float* aL2   = (float*)(ws + OFF_AL2);
  u16*   xn    = (u16*)(ws + OFF_XN);
  u16*   xin   = (u16*)(ws + OFF_XIN);
  u16*   z     = (u16*)(ws + OFF_Z);
  u16*   u     = (u16*)(ws + OFF_U);
  u16*   dblDT = (u16*)(ws + OFF_DBLDT);
  float* bcf   = (float*)(ws + OFF_BCF);
  u16*   delta = (u16*)(ws + OFF_DELTA);
  float* P     = (float*)(ws + OFF_P);
  float* CC    = (float*)(ws + OFF_CC);
  u16*   yg    = xin;   // x_in dead after conv
  u16*   ytmp  = xn;    // xn dead after GEMM1

  wconv_k<<<1760, 256, 0, stream>>>(inw, xpw, dtw, opw, alog, W, aL2);
  ln_k<<<dim3(Tn/64, Bn), 256, 0, stream>>>(x, lnw, lnb, xn);
  // in_proj: (32768x256) @ (1024x256)^T -> split x_in / z
  gemm_k<128,2><<<dim3(MTOT/128, 8), 256, 0, stream>>>(xn, 256, W, 256, xin, z, nullptr, 512, nullptr, 256);
  conv_k<<<dim3(Tn/32, 8, Bn), 256, 0, stream>>>(xin, cw, cb, u);
  // x_proj (padded to N=64): u @ Wxpp^T -> dt (bf16, 32/row) + B|C (f32, 32/row)
  gemm_k<64,3><<<dim3(MTOT/128, 1), 256, 0, stream>>>(u, 512, W + 262144, 512, dblDT, nullptr, bcf, 32, nullptr, 512);
  // dt_proj (K padded to 32) + softplus -> delta
  gemm_k<128,1><<<dim3(MTOT/128, 4), 256, 0, stream>>>(dblDT, 32, W + 294912, 32, delta, nullptr, nullptr, 512, dtb, 32);
  scanA_k<<<dim3(CH, 2, Bn), 256, 0, stream>>>(delta, u, bcf, aL2, P, CC);
  scanB_k<<<32, 256, 0, stream>>>(P, CC);
  scanC_k<<<dim3(CH, 2, Bn), 256, 0, stream>>>(delta, u, bcf, z, aL2, P, Dp, yg);
  // out_proj: yg @ Wop^T -> ytmp (B,T,256)
  gemm_k<128,0><<<dim3(MTOT/128, 2), 256, 0, stream>>>(yg, 512, W + 311296, 512, ytmp, nullptr, nullptr, 256, nullptr, 512);
  transres_k<<<dim3(Tn/64, 4, Bn), 256, 0, stream>>>(ytmp, x, out);
}